// Round 1
// baseline (7693.819 us; speedup 1.0000x reference)
//
#include <hip/hip_runtime.h>
#include <math.h>

#define HH 376
#define WW 376
#define HWSZ (HH*WW)          // 141376
#define NSC (3*HWSZ)          // 424128
#define TW 32
#define TH 16
#define KTOP 500
#define CAND_CAP 65536
#define SORT_M 4096
#define NBIN 65536

// ---------------------------------------------------------------------------
// conv16: 3x3 SAME conv, block computes a 32x16 pixel tile for 16 output
// channels (blockIdx.z selects the 16-oc group). Thread = 1 column x 16 rows
// x 2 ocs (32 accumulators). Input tile + weights staged in LDS; weights
// pulled into registers per input channel.
// ---------------------------------------------------------------------------
template<int IC, int ICB, bool BN_RELU>
__global__ __launch_bounds__(256) void conv16_kernel(
    const float* __restrict__ in,   // [IC][H][W]
    const float* __restrict__ wt,   // [OCtot][IC][3][3]
    const float* __restrict__ bn,   // [4][OCtot] (gamma,beta,mean,var)
    float* __restrict__ out,        // [OCtot][H][W]
    int octot)
{
    __shared__ float s_in[ICB][TH+2][TW+2];
    __shared__ float s_w[16][ICB][9];

    const int tid = threadIdx.x;
    const int x0 = blockIdx.x * TW;
    const int y0 = blockIdx.y * TH;
    const int ocbase = blockIdx.z * 16;
    const int lx = tid & 31;
    const int sl = tid >> 5;          // 0..7
    const int ocA = sl * 2;
    const int ocB = sl * 2 + 1;

    float accA[TH], accB[TH];
#pragma unroll
    for (int j = 0; j < TH; j++) { accA[j] = 0.f; accB[j] = 0.f; }

    for (int ic0 = 0; ic0 < IC; ic0 += ICB) {
        // ---- stage input tile (with halo, zero-padded) ----
        const int NLOAD = ICB * (TH+2) * (TW+2);
        for (int idx = tid; idx < NLOAD; idx += 256) {
            int ic  = idx / ((TH+2)*(TW+2));
            int rem = idx % ((TH+2)*(TW+2));
            int r   = rem / (TW+2);
            int c   = rem % (TW+2);
            int gy  = y0 + r - 1;
            int gx  = x0 + c - 1;
            float v = 0.f;
            if (gy >= 0 && gy < HH && gx >= 0 && gx < WW)
                v = in[(ic0+ic)*HWSZ + gy*WW + gx];
            s_in[ic][r][c] = v;
        }
        // ---- stage weights ----
        const int NW = 16 * ICB * 9;
        for (int idx = tid; idx < NW; idx += 256) {
            int oc  = idx / (ICB*9);
            int rem = idx % (ICB*9);
            int ic  = rem / 9;
            int k   = rem % 9;
            s_w[oc][ic][k] = wt[((ocbase+oc)*IC + (ic0+ic))*9 + k];
        }
        __syncthreads();

#pragma unroll
        for (int ic = 0; ic < ICB; ic++) {
            float wa[9], wb[9];
#pragma unroll
            for (int k = 0; k < 9; k++) { wa[k] = s_w[ocA][ic][k]; wb[k] = s_w[ocB][ic][k]; }
#pragma unroll
            for (int r = 0; r < TH+2; r++) {
                float v0 = s_in[ic][r][lx];
                float v1 = s_in[ic][r][lx+1];
                float v2 = s_in[ic][r][lx+2];
#pragma unroll
                for (int ky = 0; ky < 3; ky++) {
                    int j = r - ky;                 // output row index in tile
                    if (j >= 0 && j < TH) {
                        accA[j] += wa[ky*3+0]*v0 + wa[ky*3+1]*v1 + wa[ky*3+2]*v2;
                        accB[j] += wb[ky*3+0]*v0 + wb[ky*3+1]*v1 + wb[ky*3+2]*v2;
                    }
                }
            }
        }
        __syncthreads();
    }

    // ---- epilogue: BN + ReLU, store ----
    const int gx = x0 + lx;
    if (gx < WW) {
        float sA = 1.f, shA = 0.f, sB = 1.f, shB = 0.f;
        if (BN_RELU) {
            int oA = ocbase + ocA, oB = ocbase + ocB;
            float gA = bn[0*octot+oA], bA = bn[1*octot+oA], mA = bn[2*octot+oA], vA = bn[3*octot+oA];
            float gB = bn[0*octot+oB], bB = bn[1*octot+oB], mB = bn[2*octot+oB], vB = bn[3*octot+oB];
            sA = gA * rsqrtf(vA + 1e-5f);  shA = bA - mA * sA;
            sB = gB * rsqrtf(vB + 1e-5f);  shB = bB - mB * sB;
        }
#pragma unroll
        for (int j = 0; j < TH; j++) {
            int gy = y0 + j;
            if (gy < HH) {
                float a = accA[j], b = accB[j];
                if (BN_RELU) { a = fmaxf(a*sA + shA, 0.f); b = fmaxf(b*sB + shB, 0.f); }
                out[(ocbase+ocA)*HWSZ + gy*WW + gx] = a;
                out[(ocbase+ocB)*HWSZ + gy*WW + gx] = b;
            }
        }
    }
}

// ---------------------------------------------------------------------------
// convhead: final 3x3 conv, up to 3 output channels + bias (no BN/ReLU).
// Thread = 1 column x 8 rows x 1 oc. slot = tid>>5: oc = slot&3 (3 used),
// row-half = slot>>2.
// ---------------------------------------------------------------------------
template<int IC, int ICB>
__global__ __launch_bounds__(256) void convhead_kernel(
    const float* __restrict__ in,   // [IC][H][W]
    const float* __restrict__ wt,   // [3][IC][9]
    const float* __restrict__ bias, // [3]
    float* __restrict__ out,        // [nch][H][W]
    int nch)
{
    __shared__ float s_in[ICB][TH+2][TW+2];
    __shared__ float s_w[3][ICB][9];

    const int tid = threadIdx.x;
    const int x0 = blockIdx.x * TW;
    const int y0 = blockIdx.y * TH;
    const int lx = tid & 31;
    const int sl = tid >> 5;
    int oc = sl & 3;
    const bool ocvalid = (oc < nch) && (oc < 3);
    if (oc > 2) oc = 2;
    const int h0 = (sl >> 2) * 8;

    float acc[8];
#pragma unroll
    for (int j = 0; j < 8; j++) acc[j] = 0.f;

    for (int ic0 = 0; ic0 < IC; ic0 += ICB) {
        const int NLOAD = ICB * (TH+2) * (TW+2);
        for (int idx = tid; idx < NLOAD; idx += 256) {
            int ic  = idx / ((TH+2)*(TW+2));
            int rem = idx % ((TH+2)*(TW+2));
            int r   = rem / (TW+2);
            int c   = rem % (TW+2);
            int gy  = y0 + r - 1;
            int gx  = x0 + c - 1;
            float v = 0.f;
            if (gy >= 0 && gy < HH && gx >= 0 && gx < WW)
                v = in[(ic0+ic)*HWSZ + gy*WW + gx];
            s_in[ic][r][c] = v;
        }
        const int NW = 3 * ICB * 9;
        for (int idx = tid; idx < NW; idx += 256) {
            int o   = idx / (ICB*9);
            int rem = idx % (ICB*9);
            int ic  = rem / 9;
            int k   = rem % 9;
            s_w[o][ic][k] = wt[(o*IC + (ic0+ic))*9 + k];
        }
        __syncthreads();

#pragma unroll
        for (int ic = 0; ic < ICB; ic++) {
            float w9[9];
#pragma unroll
            for (int k = 0; k < 9; k++) w9[k] = s_w[oc][ic][k];
#pragma unroll
            for (int r8 = 0; r8 < 10; r8++) {
                int r = h0 + r8;
                float v0 = s_in[ic][r][lx];
                float v1 = s_in[ic][r][lx+1];
                float v2 = s_in[ic][r][lx+2];
#pragma unroll
                for (int ky = 0; ky < 3; ky++) {
                    int j = r8 - ky;
                    if (j >= 0 && j < 8)
                        acc[j] += w9[ky*3+0]*v0 + w9[ky*3+1]*v1 + w9[ky*3+2]*v2;
                }
            }
        }
        __syncthreads();
    }

    const int gx = x0 + lx;
    if (gx < WW && ocvalid) {
        float b = bias[oc];
#pragma unroll
        for (int j = 0; j < 8; j++) {
            int gy = y0 + h0 + j;
            if (gy < HH) out[oc*HWSZ + gy*WW + gx] = acc[j] + b;
        }
    }
}

// ---------------------------------------------------------------------------
// Top-K machinery. Key observation: all sigmoid scores are positive floats,
// so the f32 bit pattern is order-isomorphic to the value. 64-bit sort key
// (score_bits<<32)|(0xFFFFFFFF-idx) sorted descending reproduces
// jax.lax.top_k (descending value, ties -> lower index first).
// ---------------------------------------------------------------------------
__global__ void hist_kernel(const float* __restrict__ hm, unsigned* __restrict__ hist)
{
    int i = blockIdx.x * 256 + threadIdx.x;
    if (i < NSC) {
        float sc = 1.f / (1.f + expf(-hm[i]));
        unsigned key = __float_as_uint(sc);
        atomicAdd(&hist[key >> 16], 1u);
    }
}

__global__ void scan_kernel(const unsigned* __restrict__ hist, unsigned* __restrict__ meta)
{
    __shared__ unsigned part[1024];
    __shared__ unsigned suf[1024];
    const int t = threadIdx.x;
    unsigned ssum = 0;
    for (int b = t*64; b < t*64 + 64; b++) ssum += hist[b];
    part[t] = ssum;
    __syncthreads();
    if (t == 0) {
        unsigned run = 0;
        for (int i = 1023; i >= 0; i--) { suf[i] = run; run += part[i]; }
        int tc = 0;
        for (int i = 1023; i >= 0; i--) {
            if (suf[i] < KTOP && suf[i] + part[i] >= KTOP) { tc = i; break; }
        }
        unsigned c = suf[tc];
        unsigned B = tc * 64;
        for (int b = tc*64 + 63; b >= tc*64; b--) {
            c += hist[b];
            if (c >= KTOP) { B = (unsigned)b; break; }
        }
        meta[0] = B;   // threshold bucket
        meta[1] = 0;   // candidate counter
    }
}

__global__ void collect_kernel(const float* __restrict__ hm,
                               unsigned* __restrict__ meta,
                               unsigned long long* __restrict__ cand)
{
    int i = blockIdx.x * 256 + threadIdx.x;
    if (i >= NSC) return;
    float sc = 1.f / (1.f + expf(-hm[i]));
    unsigned key = __float_as_uint(sc);
    if ((key >> 16) >= meta[0]) {
        unsigned pos = atomicAdd(&meta[1], 1u);
        if (pos < CAND_CAP)
            cand[pos] = ((unsigned long long)key << 32) | (unsigned)(0xFFFFFFFFu - (unsigned)i);
    }
}

__global__ void topk_decode_kernel(const unsigned* __restrict__ meta,
                                   const unsigned long long* __restrict__ cand,
                                   const float* __restrict__ P,   // 12 planes
                                   float* __restrict__ dout)
{
    extern __shared__ unsigned long long s[];   // SORT_M entries
    __shared__ unsigned long long red[512];
    const int t = threadIdx.x;
    unsigned n = meta[1];
    if (n > CAND_CAP) n = CAND_CAP;

    if (n <= SORT_M) {
        for (int i = t; i < SORT_M; i += 512) s[i] = (i < (int)n) ? cand[i] : 0ULL;
        __syncthreads();
        for (unsigned k = 2; k <= SORT_M; k <<= 1) {
            for (unsigned j = k >> 1; j > 0; j >>= 1) {
                for (unsigned i = t; i < SORT_M; i += 512) {
                    unsigned ixj = i ^ j;
                    if (ixj > i) {
                        unsigned long long a = s[i], b = s[ixj];
                        bool desc = ((i & k) == 0);
                        if (desc ? (a < b) : (a > b)) { s[i] = b; s[ixj] = a; }
                    }
                }
                __syncthreads();
            }
        }
    } else {
        // fallback (never expected): O(K*n) selection
        unsigned long long last = 0xFFFFFFFFFFFFFFFFULL;
        for (int slot = 0; slot < KTOP; slot++) {
            unsigned long long best = 0;
            for (unsigned i = t; i < n; i += 512) {
                unsigned long long v = cand[i];
                if (v < last && v > best) best = v;
            }
            red[t] = best;
            __syncthreads();
            for (int off = 256; off > 0; off >>= 1) {
                if (t < off) { if (red[t+off] > red[t]) red[t] = red[t+off]; }
                __syncthreads();
            }
            if (t == 0) s[slot] = red[0];
            last = red[0];
            __syncthreads();
        }
    }
    __syncthreads();

    if (t < KTOP) {
        unsigned long long e = s[t];
        unsigned key = (unsigned)(e >> 32);
        unsigned idx = 0xFFFFFFFFu - (unsigned)(e & 0xFFFFFFFFu);
        int cls = (int)(idx / HWSZ);
        int sp  = (int)(idx % HWSZ);
        float ys = (float)(sp / WW);
        float xs = (float)(sp % WW);
        float shm = __uint_as_float(key);

        float ct0 = P[3*HWSZ + sp], ct1 = P[4*HWSZ + sp];
        float cz  = P[5*HWSZ + sp];
        float d0  = expf(P[6*HWSZ + sp]);
        float d1  = expf(P[7*HWSZ + sp]);
        float d2  = expf(P[8*HWSZ + sp]);
        float r0  = P[9*HWSZ + sp], r1 = P[10*HWSZ + sp];
        float iou = P[11*HWSZ + sp];

        float xg = (xs + ct0) * 4.0f * 0.1f + (-75.2f);
        float yg = (ys + ct1) * 4.0f * 0.1f + (-75.2f);
        float heading = atan2f(r1, r0);
        iou = (iou + 1.f) * 0.5f;
        iou = fminf(fmaxf(iou, 0.f), 1.f);
        const float RECT[3] = {0.68f, 0.71f, 0.65f};
        float r = RECT[cls];
        float score = powf(shm, 1.f - r) * powf(iou, r);
        score = (score > 0.1f) ? score : 0.f;

        dout[t*7+0] = xg;  dout[t*7+1] = yg;  dout[t*7+2] = cz;
        dout[t*7+3] = d0;  dout[t*7+4] = d1;  dout[t*7+5] = d2;
        dout[t*7+6] = heading;
        dout[3500 + t] = score;
        dout[4000 + t] = (float)cls;
    }
}

// ---------------------------------------------------------------------------
extern "C" void kernel_launch(void* const* d_in, const int* in_sizes, int n_in,
                              void* d_out, int out_size, void* d_ws, size_t ws_size,
                              hipStream_t stream)
{
    const float* x    = (const float*)d_in[0];   // [256][376][376]
    const float* W_sh = (const float*)d_in[1];   // [64][256][9]
    const float* bn_sh= (const float*)d_in[2];   // [4][64]
    const float* W1s  = (const float*)d_in[3];   // [6][64][64][9]
    const float* bn1s = (const float*)d_in[4];   // [6][4][64]
    const float* W2s  = (const float*)d_in[5];   // [6][3][64][9]
    const float* b2s  = (const float*)d_in[6];   // [6][3]
    float* dout = (float*)d_out;

    char* ws = (char*)d_ws;
    const size_t OFF_SHARED = 0;
    const size_t OFF_H1     = OFF_SHARED + (size_t)64*HWSZ*4;   // 36,192,256
    const size_t OFF_OUTS   = OFF_H1     + (size_t)64*HWSZ*4;
    const size_t OFF_HIST   = OFF_OUTS   + (size_t)12*HWSZ*4;
    const size_t OFF_META   = OFF_HIST   + (size_t)NBIN*4;
    const size_t OFF_CAND   = OFF_META   + 256;

    float* f_shared = (float*)(ws + OFF_SHARED);
    float* f_h1     = (float*)(ws + OFF_H1);
    float* f_outs   = (float*)(ws + OFF_OUTS);
    unsigned* hist  = (unsigned*)(ws + OFF_HIST);
    unsigned* meta  = (unsigned*)(ws + OFF_META);
    unsigned long long* cand = (unsigned long long*)(ws + OFF_CAND);

    dim3 gconv(12, 24, 4);     // 376/32=11.75, 376/16=23.5, 64/16
    dim3 ghead(12, 24, 1);
    dim3 blk(256);

    // zero the histogram (re-poisoned to 0xAA before every timed launch)
    hipMemsetAsync(hist, 0, (size_t)NBIN*4, stream);

    // shared conv: 256 -> 64, BN+ReLU
    conv16_kernel<256, 8, true><<<gconv, blk, 0, stream>>>(x, W_sh, bn_sh, f_shared, 64);

    // branch heads
    const int planebase[6] = {0, 3, 5, 6, 9, 11};
    const int nch[6]       = {3, 2, 1, 3, 2, 1};
    for (int i = 0; i < 6; i++) {
        conv16_kernel<64, 8, true><<<gconv, blk, 0, stream>>>(
            f_shared, W1s + (size_t)i*64*64*9, bn1s + (size_t)i*4*64, f_h1, 64);
        convhead_kernel<64, 8><<<ghead, blk, 0, stream>>>(
            f_h1, W2s + (size_t)i*3*64*9, b2s + (size_t)i*3,
            f_outs + (size_t)planebase[i]*HWSZ, nch[i]);
    }

    // top-k select + decode (hm logits are planes 0..2 of f_outs)
    dim3 gscan((NSC + 255)/256);
    hist_kernel<<<gscan, blk, 0, stream>>>(f_outs, hist);
    scan_kernel<<<1, 1024, 0, stream>>>(hist, meta);
    collect_kernel<<<gscan, blk, 0, stream>>>(f_outs, meta, cand);
    topk_decode_kernel<<<1, 512, SORT_M*sizeof(unsigned long long), stream>>>(
        meta, cand, f_outs, dout);

    (void)in_sizes; (void)n_in; (void)out_size; (void)ws_size;
}

// Round 2
// 3435.152 us; speedup vs baseline: 2.2397x; 2.2397x over previous
//
#include <hip/hip_runtime.h>
#include <math.h>

#define HH 376
#define WW 376
#define HWSZ (HH*WW)          // 141376
#define NSC (3*HWSZ)          // 424128
#define KTOP 500
#define CAND_CAP 65536
#define SORT_M 4096
#define NBIN 65536

// conv64 tiling
#define TW2 32
#define TH2 8
#define ICB2 8
#define SIN_W 34              // TW2+2
#define SIN_H 10              // TH2+2
#define NLOAD2 (ICB2*SIN_H*SIN_W)   // 2720
#define NPF ((NLOAD2+255)/256)      // 11

// head tiling
#define HICB 2
#define HTH 64
#define H_SINH 66
#define H_NLOAD (HICB*H_SINH*SIN_W) // 4488
#define H_NPF ((H_NLOAD+255)/256)   // 18

// ---------------------------------------------------------------------------
// Weight reorder: [b][oc][IC][9] -> [b][chunk][icl][OC][9] so per-chunk
// staging is a contiguous float4 copy.
// ---------------------------------------------------------------------------
__global__ void reorder_w_kernel(const float* __restrict__ src, float* __restrict__ dst,
                                 int IC, int ICB, int OC, int total)
{
    int i = blockIdx.x*256 + threadIdx.x;
    if (i >= total) return;
    int per = OC*IC*9;
    int b = i / per;
    int j = i - b*per;
    int chunksz = ICB*OC*9;
    int chunk = j / chunksz;
    int r = j - chunk*chunksz;
    int icl = r / (OC*9);
    int rr = r - icl*(OC*9);
    int oc = rr / 9;
    int kk = rr - oc*9;
    int ic = chunk*ICB + icl;
    dst[i] = src[b*per + (oc*IC + ic)*9 + kk];
}

// ---------------------------------------------------------------------------
// conv64: 3x3 SAME conv, IC -> 64 oc with BN+ReLU. Block = 32x8 pixel tile,
// ALL 64 ocs. Thread = 1 col x 8 rows x 8 ocs (64 acc). Register-prefetch
// software pipeline on the input staging; weights pre-reordered for a
// float4 LDS copy.
// ---------------------------------------------------------------------------
template<int IC>
__global__ __launch_bounds__(256,2) void conv64_kernel(
    const float* __restrict__ in,    // [IC][H][W]
    const float* __restrict__ rw,    // reordered weights [IC/8][8][64][9]
    const float* __restrict__ bnp,   // [4][64]
    float* __restrict__ out)         // [64][H][W]
{
    __shared__ float s_in[ICB2][SIN_H][SIN_W];
    __shared__ float s_w[ICB2][64][9];

    const int tid  = threadIdx.x;
    const int x0   = blockIdx.x * TW2;
    const int y0   = blockIdx.y * TH2;
    const int lx   = tid & 31;
    const int slot = tid >> 5;          // 0..7 -> ocs slot*8..slot*8+7

    float acc[8][8];
#pragma unroll
    for (int o = 0; o < 8; o++)
#pragma unroll
        for (int j = 0; j < 8; j++) acc[o][j] = 0.f;

    // ---- static prefetch pointer setup ----
    const float* pfp[NPF];
    bool pfv[NPF];
#pragma unroll
    for (int k = 0; k < NPF; k++) {
        int idx = tid + k*256;
        int ic  = idx / (SIN_H*SIN_W);
        int rem = idx - ic*(SIN_H*SIN_W);
        int r   = rem / SIN_W;
        int c   = rem - r*SIN_W;
        int gy  = y0 + r - 1;
        int gx  = x0 + c - 1;
        pfv[k] = (idx < NLOAD2) && gy >= 0 && gy < HH && gx >= 0 && gx < WW;
        pfp[k] = in + ((long)ic*HWSZ + (long)gy*WW + gx);
    }
    float pf[NPF];
    auto do_prefetch = [&]() {
#pragma unroll
        for (int k = 0; k < NPF; k++) {
            pf[k] = pfv[k] ? pfp[k][0] : 0.f;
            pfp[k] += (long)ICB2*HWSZ;
        }
    };
    do_prefetch();

    for (int ic0 = 0; ic0 < IC; ic0 += ICB2) {
        __syncthreads();                      // previous compute done
        // store prefetched inputs
#pragma unroll
        for (int k = 0; k < NPF; k++) {
            int idx = tid + k*256;
            if (idx < NLOAD2) (&s_in[0][0][0])[idx] = pf[k];
        }
        // stage weights (contiguous chunk, float4)
        {
            const float4* wsrc = (const float4*)(rw + (size_t)(ic0/ICB2)*(ICB2*64*9));
            float4* wdst = (float4*)&s_w[0][0][0];
#pragma unroll
            for (int k = 0; k < 5; k++) {
                int idx = tid + k*256;
                if (idx < (ICB2*64*9)/4) wdst[idx] = wsrc[idx];
            }
        }
        __syncthreads();
        if (ic0 + ICB2 < IC) do_prefetch();   // overlap next chunk's loads with compute

#pragma unroll 1
        for (int ic = 0; ic < ICB2; ic++) {
            float vin[SIN_H][3];
#pragma unroll
            for (int r = 0; r < SIN_H; r++) {
                vin[r][0] = s_in[ic][r][lx];
                vin[r][1] = s_in[ic][r][lx+1];
                vin[r][2] = s_in[ic][r][lx+2];
            }
#pragma unroll
            for (int o = 0; o < 8; o++) {
                const float* wp = &s_w[ic][slot*8+o][0];
                float w0=wp[0],w1=wp[1],w2=wp[2],w3=wp[3],w4=wp[4],
                      w5=wp[5],w6=wp[6],w7=wp[7],w8=wp[8];
#pragma unroll
                for (int j = 0; j < 8; j++) {
                    float s = acc[o][j];
                    s = fmaf(w0, vin[j  ][0], s);
                    s = fmaf(w1, vin[j  ][1], s);
                    s = fmaf(w2, vin[j  ][2], s);
                    s = fmaf(w3, vin[j+1][0], s);
                    s = fmaf(w4, vin[j+1][1], s);
                    s = fmaf(w5, vin[j+1][2], s);
                    s = fmaf(w6, vin[j+2][0], s);
                    s = fmaf(w7, vin[j+2][1], s);
                    s = fmaf(w8, vin[j+2][2], s);
                    acc[o][j] = s;
                }
            }
        }
    }

    // ---- epilogue: BN + ReLU ----
    const int gx = x0 + lx;
    if (gx < WW) {
#pragma unroll
        for (int o = 0; o < 8; o++) {
            int oc = slot*8 + o;
            float g = bnp[oc], b = bnp[64+oc], m = bnp[128+oc], v = bnp[192+oc];
            float sc = g * rsqrtf(v + 1e-5f);
            float sh = b - m * sc;
#pragma unroll
            for (int j = 0; j < 8; j++) {
                float val = fmaxf(fmaf(acc[o][j], sc, sh), 0.f);
                out[(size_t)oc*HWSZ + (size_t)(y0+j)*WW + gx] = val;
            }
        }
    }
}

// ---------------------------------------------------------------------------
// head: 3x3 conv 64 -> nch (<=3) + bias. Block = 32x64 tile; thread = 1 col
// x 8 rows x 3 ocs. ICB=2 chunks with the same prefetch pipeline.
// ---------------------------------------------------------------------------
__global__ __launch_bounds__(256,3) void head_kernel(
    const float* __restrict__ in,    // [64][H][W]
    const float* __restrict__ rw,    // reordered [32][2][3][9]
    const float* __restrict__ bias,  // [3]
    float* __restrict__ out,         // [nch][H][W]
    int nch)
{
    __shared__ float s_in[HICB][H_SINH][SIN_W];
    __shared__ float s_w[HICB][3][9];

    const int tid  = threadIdx.x;
    const int x0   = blockIdx.x * TW2;
    const int y0   = blockIdx.y * HTH;
    const int lx   = tid & 31;
    const int slot = tid >> 5;          // row octet

    float acc[3][8];
#pragma unroll
    for (int o = 0; o < 3; o++)
#pragma unroll
        for (int j = 0; j < 8; j++) acc[o][j] = 0.f;

    const float* pfp[H_NPF];
    bool pfv[H_NPF];
#pragma unroll
    for (int k = 0; k < H_NPF; k++) {
        int idx = tid + k*256;
        int ic  = idx / (H_SINH*SIN_W);
        int rem = idx - ic*(H_SINH*SIN_W);
        int r   = rem / SIN_W;
        int c   = rem - r*SIN_W;
        int gy  = y0 + r - 1;
        int gx  = x0 + c - 1;
        pfv[k] = (idx < H_NLOAD) && gy >= 0 && gy < HH && gx >= 0 && gx < WW;
        pfp[k] = in + ((long)ic*HWSZ + (long)gy*WW + gx);
    }
    float pf[H_NPF];
    auto do_prefetch = [&]() {
#pragma unroll
        for (int k = 0; k < H_NPF; k++) {
            pf[k] = pfv[k] ? pfp[k][0] : 0.f;
            pfp[k] += (long)HICB*HWSZ;
        }
    };
    do_prefetch();

    for (int ic0 = 0; ic0 < 64; ic0 += HICB) {
        __syncthreads();
#pragma unroll
        for (int k = 0; k < H_NPF; k++) {
            int idx = tid + k*256;
            if (idx < H_NLOAD) (&s_in[0][0][0])[idx] = pf[k];
        }
        if (tid < HICB*3*9)
            (&s_w[0][0][0])[tid] = rw[(size_t)(ic0/HICB)*(HICB*3*9) + tid];
        __syncthreads();
        if (ic0 + HICB < 64) do_prefetch();

#pragma unroll 1
        for (int ic = 0; ic < HICB; ic++) {
            float vin[SIN_H][3];
#pragma unroll
            for (int r = 0; r < SIN_H; r++) {
                vin[r][0] = s_in[ic][slot*8 + r][lx];
                vin[r][1] = s_in[ic][slot*8 + r][lx+1];
                vin[r][2] = s_in[ic][slot*8 + r][lx+2];
            }
#pragma unroll
            for (int o = 0; o < 3; o++) {
                const float* wp = &s_w[ic][o][0];
                float w0=wp[0],w1=wp[1],w2=wp[2],w3=wp[3],w4=wp[4],
                      w5=wp[5],w6=wp[6],w7=wp[7],w8=wp[8];
#pragma unroll
                for (int j = 0; j < 8; j++) {
                    float s = acc[o][j];
                    s = fmaf(w0, vin[j  ][0], s);
                    s = fmaf(w1, vin[j  ][1], s);
                    s = fmaf(w2, vin[j  ][2], s);
                    s = fmaf(w3, vin[j+1][0], s);
                    s = fmaf(w4, vin[j+1][1], s);
                    s = fmaf(w5, vin[j+1][2], s);
                    s = fmaf(w6, vin[j+2][0], s);
                    s = fmaf(w7, vin[j+2][1], s);
                    s = fmaf(w8, vin[j+2][2], s);
                    acc[o][j] = s;
                }
            }
        }
    }

    const int gx = x0 + lx;
    if (gx < WW) {
#pragma unroll
        for (int o = 0; o < 3; o++) {
            if (o < nch) {
                float bo = bias[o];
#pragma unroll
                for (int j = 0; j < 8; j++) {
                    int gy = y0 + slot*8 + j;
                    if (gy < HH)
                        out[(size_t)o*HWSZ + (size_t)gy*WW + gx] = acc[o][j] + bo;
                }
            }
        }
    }
}

// ---------------------------------------------------------------------------
// Top-K machinery (unchanged from round 1 — verified correct).
// ---------------------------------------------------------------------------
__global__ void hist_kernel(const float* __restrict__ hm, unsigned* __restrict__ hist)
{
    int i = blockIdx.x * 256 + threadIdx.x;
    if (i < NSC) {
        float sc = 1.f / (1.f + expf(-hm[i]));
        unsigned key = __float_as_uint(sc);
        atomicAdd(&hist[key >> 16], 1u);
    }
}

__global__ void scan_kernel(const unsigned* __restrict__ hist, unsigned* __restrict__ meta)
{
    __shared__ unsigned part[1024];
    __shared__ unsigned suf[1024];
    const int t = threadIdx.x;
    unsigned ssum = 0;
    for (int b = t*64; b < t*64 + 64; b++) ssum += hist[b];
    part[t] = ssum;
    __syncthreads();
    if (t == 0) {
        unsigned run = 0;
        for (int i = 1023; i >= 0; i--) { suf[i] = run; run += part[i]; }
        int tc = 0;
        for (int i = 1023; i >= 0; i--) {
            if (suf[i] < KTOP && suf[i] + part[i] >= KTOP) { tc = i; break; }
        }
        unsigned c = suf[tc];
        unsigned B = tc * 64;
        for (int b = tc*64 + 63; b >= tc*64; b--) {
            c += hist[b];
            if (c >= KTOP) { B = (unsigned)b; break; }
        }
        meta[0] = B;
        meta[1] = 0;
    }
}

__global__ void collect_kernel(const float* __restrict__ hm,
                               unsigned* __restrict__ meta,
                               unsigned long long* __restrict__ cand)
{
    int i = blockIdx.x * 256 + threadIdx.x;
    if (i >= NSC) return;
    float sc = 1.f / (1.f + expf(-hm[i]));
    unsigned key = __float_as_uint(sc);
    if ((key >> 16) >= meta[0]) {
        unsigned pos = atomicAdd(&meta[1], 1u);
        if (pos < CAND_CAP)
            cand[pos] = ((unsigned long long)key << 32) | (unsigned)(0xFFFFFFFFu - (unsigned)i);
    }
}

__global__ void topk_decode_kernel(const unsigned* __restrict__ meta,
                                   const unsigned long long* __restrict__ cand,
                                   const float* __restrict__ P,
                                   float* __restrict__ dout)
{
    extern __shared__ unsigned long long s[];
    __shared__ unsigned long long red[512];
    const int t = threadIdx.x;
    unsigned n = meta[1];
    if (n > CAND_CAP) n = CAND_CAP;

    if (n <= SORT_M) {
        for (int i = t; i < SORT_M; i += 512) s[i] = (i < (int)n) ? cand[i] : 0ULL;
        __syncthreads();
        for (unsigned k = 2; k <= SORT_M; k <<= 1) {
            for (unsigned j = k >> 1; j > 0; j >>= 1) {
                for (unsigned i = t; i < SORT_M; i += 512) {
                    unsigned ixj = i ^ j;
                    if (ixj > i) {
                        unsigned long long a = s[i], b = s[ixj];
                        bool desc = ((i & k) == 0);
                        if (desc ? (a < b) : (a > b)) { s[i] = b; s[ixj] = a; }
                    }
                }
                __syncthreads();
            }
        }
    } else {
        unsigned long long last = 0xFFFFFFFFFFFFFFFFULL;
        for (int slot = 0; slot < KTOP; slot++) {
            unsigned long long best = 0;
            for (unsigned i = t; i < n; i += 512) {
                unsigned long long v = cand[i];
                if (v < last && v > best) best = v;
            }
            red[t] = best;
            __syncthreads();
            for (int off = 256; off > 0; off >>= 1) {
                if (t < off) { if (red[t+off] > red[t]) red[t] = red[t+off]; }
                __syncthreads();
            }
            if (t == 0) s[slot] = red[0];
            last = red[0];
            __syncthreads();
        }
    }
    __syncthreads();

    if (t < KTOP) {
        unsigned long long e = s[t];
        unsigned key = (unsigned)(e >> 32);
        unsigned idx = 0xFFFFFFFFu - (unsigned)(e & 0xFFFFFFFFu);
        int cls = (int)(idx / HWSZ);
        int sp  = (int)(idx % HWSZ);
        float ys = (float)(sp / WW);
        float xs = (float)(sp % WW);
        float shm = __uint_as_float(key);

        float ct0 = P[3*HWSZ + sp], ct1 = P[4*HWSZ + sp];
        float cz  = P[5*HWSZ + sp];
        float d0  = expf(P[6*HWSZ + sp]);
        float d1  = expf(P[7*HWSZ + sp]);
        float d2  = expf(P[8*HWSZ + sp]);
        float r0  = P[9*HWSZ + sp], r1 = P[10*HWSZ + sp];
        float iou = P[11*HWSZ + sp];

        float xg = (xs + ct0) * 4.0f * 0.1f + (-75.2f);
        float yg = (ys + ct1) * 4.0f * 0.1f + (-75.2f);
        float heading = atan2f(r1, r0);
        iou = (iou + 1.f) * 0.5f;
        iou = fminf(fmaxf(iou, 0.f), 1.f);
        const float RECT[3] = {0.68f, 0.71f, 0.65f};
        float r = RECT[cls];
        float score = powf(shm, 1.f - r) * powf(iou, r);
        score = (score > 0.1f) ? score : 0.f;

        dout[t*7+0] = xg;  dout[t*7+1] = yg;  dout[t*7+2] = cz;
        dout[t*7+3] = d0;  dout[t*7+4] = d1;  dout[t*7+5] = d2;
        dout[t*7+6] = heading;
        dout[3500 + t] = score;
        dout[4000 + t] = (float)cls;
    }
}

// ---------------------------------------------------------------------------
extern "C" void kernel_launch(void* const* d_in, const int* in_sizes, int n_in,
                              void* d_out, int out_size, void* d_ws, size_t ws_size,
                              hipStream_t stream)
{
    const float* x    = (const float*)d_in[0];   // [256][376][376]
    const float* W_sh = (const float*)d_in[1];   // [64][256][9]
    const float* bn_sh= (const float*)d_in[2];   // [4][64]
    const float* W1s  = (const float*)d_in[3];   // [6][64][64][9]
    const float* bn1s = (const float*)d_in[4];   // [6][4][64]
    const float* W2s  = (const float*)d_in[5];   // [6][3][64][9]
    const float* b2s  = (const float*)d_in[6];   // [6][3]
    float* dout = (float*)d_out;

    char* ws = (char*)d_ws;
    const size_t OFF_SHARED = 0;
    const size_t OFF_H1     = OFF_SHARED + (size_t)64*HWSZ*4;   // 36.19MB
    const size_t OFF_OUTS   = OFF_H1     + (size_t)64*HWSZ*4;
    const size_t OFF_HIST   = OFF_OUTS   + (size_t)12*HWSZ*4;
    const size_t OFF_META   = OFF_HIST   + (size_t)NBIN*4;
    const size_t OFF_CAND   = OFF_META   + 256;
    // reordered weights OVERLAP hist/meta/cand region: rw used only during
    // convs, hist/cand only after (hist memset happens after the heads).
    const size_t OFF_RWSH   = OFF_HIST;                          // 147456 f
    const size_t OFF_RWBR   = OFF_RWSH + (size_t)147456*4;       // 221184 f
    const size_t OFF_RWHD   = OFF_RWBR + (size_t)221184*4;       // 10368 f

    float* f_shared = (float*)(ws + OFF_SHARED);
    float* f_h1     = (float*)(ws + OFF_H1);
    float* f_outs   = (float*)(ws + OFF_OUTS);
    unsigned* hist  = (unsigned*)(ws + OFF_HIST);
    unsigned* meta  = (unsigned*)(ws + OFF_META);
    unsigned long long* cand = (unsigned long long*)(ws + OFF_CAND);
    float* rwsh = (float*)(ws + OFF_RWSH);
    float* rwbr = (float*)(ws + OFF_RWBR);
    float* rwhd = (float*)(ws + OFF_RWHD);

    dim3 blk(256);

    // ---- weight reorders (before convs; they share memory with hist/cand) ----
    reorder_w_kernel<<<(147456+255)/256, blk, 0, stream>>>(W_sh, rwsh, 256, ICB2, 64, 147456);
    reorder_w_kernel<<<(221184+255)/256, blk, 0, stream>>>(W1s,  rwbr,  64, ICB2, 64, 221184);
    reorder_w_kernel<<<(10368+255)/256,  blk, 0, stream>>>(W2s,  rwhd,  64, HICB,  3, 10368);

    // ---- convs ----
    dim3 gconv(12, 47);
    dim3 ghead(12, 6);
    conv64_kernel<256><<<gconv, blk, 0, stream>>>(x, rwsh, bn_sh, f_shared);

    const int planebase[6] = {0, 3, 5, 6, 9, 11};
    const int nch[6]       = {3, 2, 1, 3, 2, 1};
    for (int i = 0; i < 6; i++) {
        conv64_kernel<64><<<gconv, blk, 0, stream>>>(
            f_shared, rwbr + (size_t)i*221184/6, bn1s + (size_t)i*4*64, f_h1);
        head_kernel<<<ghead, blk, 0, stream>>>(
            f_h1, rwhd + (size_t)i*1728, b2s + (size_t)i*3,
            f_outs + (size_t)planebase[i]*HWSZ, nch[i]);
    }

    // ---- top-k select + decode (hist region free now; rw no longer needed) ----
    hipMemsetAsync(hist, 0, (size_t)NBIN*4, stream);
    dim3 gscan((NSC + 255)/256);
    hist_kernel<<<gscan, blk, 0, stream>>>(f_outs, hist);
    scan_kernel<<<1, 1024, 0, stream>>>(hist, meta);
    collect_kernel<<<gscan, blk, 0, stream>>>(f_outs, meta, cand);
    topk_decode_kernel<<<1, 512, SORT_M*sizeof(unsigned long long), stream>>>(
        meta, cand, f_outs, dout);

    (void)in_sizes; (void)n_in; (void)out_size; (void)ws_size;
}